// Round 2
// baseline (6417.675 us; speedup 1.0000x reference)
//
#include <hip/hip_runtime.h>
#include <hip/hip_bf16.h>
#include <math.h>

typedef __hip_bfloat16 bf16;

#define BM 64
#define BN 64
#define BK 16
#define LDP (BM + 4)   // padded LDS leading dim

enum {
    EPI_PLAIN  = 0,  // C = acc
    EPI_RELU   = 1,  // C = relu(acc + bias[n])
    EPI_TANH   = 2,  // C = tanh(acc + bias[n]) * ubar[n%8]
    EPI_NS     = 3,  // C = 2*aux1 - acc           (Newton-Schulz update)
    EPI_SCALE2 = 4,  // C = 2*acc
    EPI_ZINIT  = 5,  // C = min(acc, aux1); aux2 = 0
    EPI_ADMM   = 6,  // s=acc+aux1+aux2; d=s-aux3; aux2=max(d,0); C=aux3-|d|
    EPI_FINAL  = 7,  // out[n*M+m] = 2*acc + aux1   (transposed store, dtype per flag)
    EPI_KMAT   = 8,  // C = acc + 2*(m==n)
};

// dual-dtype input load: flag==1 -> buffer is float32, else bf16
__device__ __forceinline__ float ldf(const void* p, long i, int f32) {
    return f32 ? ((const float*)p)[i]
               : __bfloat162float(((const bf16*)p)[i]);
}

// Detect input dtype on-device: scan first 16384 16-bit slots of F as bf16.
// Real bf16 F (~N(0,1/20)) never has |x| >= 2^17 (exp>=0x90). fp32-backed
// data has random mantissa bits in every low half -> thousands of hits.
__global__ void detect_kernel(const void* Fp, int* flag) {
    __shared__ int hit;
    if (threadIdx.x == 0) hit = 0;
    __syncthreads();
    const unsigned short* u = (const unsigned short*)Fp;
    int local = 0;
    for (int i = threadIdx.x; i < 16384; i += 256) {
        int e = (u[i] >> 7) & 0xFF;
        if (e >= 0x90) local = 1;
    }
    if (local) atomicOr(&hit, 1);
    __syncthreads();
    if (threadIdx.x == 0) flag[0] = hit;
}

template<int EPI, bool TA, bool TB, bool AIN, bool BIN>
__global__ __launch_bounds__(256)
void gemm_k(const void* __restrict__ A, const void* __restrict__ B,
            float* __restrict__ Cout,
            const float* __restrict__ aux1, float* __restrict__ aux2,
            const float* __restrict__ aux3,
            const void* __restrict__ bias, const void* __restrict__ ubar,
            void* __restrict__ outb,
            const int* __restrict__ flag,
            int M, int N, int K)
{
    const int f32 = flag[0];
    __shared__ float As[BK][LDP];
    __shared__ float Bs[BK][LDP];
    const int tid = threadIdx.x;
    const int tx = tid & 15, ty = tid >> 4;
    const int m0 = blockIdx.x * BM, n0 = blockIdx.y * BN;

    float acc[4][4] = {};

    for (int k0 = 0; k0 < K; k0 += BK) {
        // ---- stage A tile -> As[k][m] ----
        if (!TA) {
            // A is [M x K] row-major; coalesce over k
            int kk = tid & 15, mbase = tid >> 4;
#pragma unroll
            for (int j = 0; j < 4; j++) {
                int m = mbase + j * 16;
                int gm = m0 + m, gk = k0 + kk;
                float v = 0.f;
                if (gm < M && gk < K) {
                    long idx = (long)gm * K + gk;
                    v = AIN ? ldf(A, idx, f32) : ((const float*)A)[idx];
                }
                As[kk][m] = v;
            }
        } else {
            // A_log[m][k] = phys[k][m], phys is [K x M]; coalesce over m
            int mm = tid & 63, kbase = tid >> 6;
#pragma unroll
            for (int j = 0; j < 4; j++) {
                int k = kbase + j * 4;
                int gm = m0 + mm, gk = k0 + k;
                float v = 0.f;
                if (gm < M && gk < K) {
                    long idx = (long)gk * M + gm;
                    v = AIN ? ldf(A, idx, f32) : ((const float*)A)[idx];
                }
                As[k][mm] = v;
            }
        }
        // ---- stage B tile -> Bs[k][n] ----
        if (!TB) {
            // B is [K x N] row-major; coalesce over n
            int nn = tid & 63, kbase = tid >> 6;
#pragma unroll
            for (int j = 0; j < 4; j++) {
                int k = kbase + j * 4;
                int gn = n0 + nn, gk = k0 + k;
                float v = 0.f;
                if (gn < N && gk < K) {
                    long idx = (long)gk * N + gn;
                    v = BIN ? ldf(B, idx, f32) : ((const float*)B)[idx];
                }
                Bs[k][nn] = v;
            }
        } else {
            // B_log[k][n] = phys[n][k], phys is [N x K]; coalesce over k
            int kk = tid & 15, nbase = tid >> 4;
#pragma unroll
            for (int j = 0; j < 4; j++) {
                int n = nbase + j * 16;
                int gn = n0 + n, gk = k0 + kk;
                float v = 0.f;
                if (gn < N && gk < K) {
                    long idx = (long)gn * K + gk;
                    v = BIN ? ldf(B, idx, f32) : ((const float*)B)[idx];
                }
                Bs[kk][n] = v;
            }
        }
        __syncthreads();

#pragma unroll
        for (int kk = 0; kk < BK; kk++) {
            float a[4], b[4];
#pragma unroll
            for (int i = 0; i < 4; i++) a[i] = As[kk][ty * 4 + i];
#pragma unroll
            for (int i = 0; i < 4; i++) b[i] = Bs[kk][tx * 4 + i];
#pragma unroll
            for (int i = 0; i < 4; i++)
#pragma unroll
                for (int j = 0; j < 4; j++)
                    acc[i][j] = fmaf(a[i], b[j], acc[i][j]);
        }
        __syncthreads();
    }

    // ---- epilogue ----
#pragma unroll
    for (int i = 0; i < 4; i++) {
        int gm = m0 + ty * 4 + i;
        if (gm >= M) continue;
#pragma unroll
        for (int j = 0; j < 4; j++) {
            int gn = n0 + tx * 4 + j;
            if (gn >= N) continue;
            long o = (long)gm * N + gn;
            float v = acc[i][j];
            if constexpr (EPI == EPI_PLAIN) {
                Cout[o] = v;
            } else if constexpr (EPI == EPI_RELU) {
                Cout[o] = fmaxf(v + ldf(bias, gn, f32), 0.f);
            } else if constexpr (EPI == EPI_TANH) {
                Cout[o] = tanhf(v + ldf(bias, gn, f32)) * ldf(ubar, gn & 7, f32);
            } else if constexpr (EPI == EPI_NS) {
                Cout[o] = 2.f * aux1[o] - v;
            } else if constexpr (EPI == EPI_SCALE2) {
                Cout[o] = 2.f * v;
            } else if constexpr (EPI == EPI_ZINIT) {
                Cout[o] = fminf(v, aux1[o]);
                aux2[o] = 0.f;
            } else if constexpr (EPI == EPI_ADMM) {
                float s = v + aux1[o] + aux2[o];
                float d = s - aux3[o];
                aux2[o] = fmaxf(d, 0.f);
                Cout[o] = aux3[o] - fabsf(d);
            } else if constexpr (EPI == EPI_FINAL) {
                float val = 2.f * v + aux1[o];
                long oo = (long)gn * M + gm;   // transposed [N x M] store
                if (f32) ((float*)outb)[oo] = val;
                else     ((bf16*)outb)[oo] = __float2bfloat16(val);
            } else if constexpr (EPI == EPI_KMAT) {
                Cout[o] = v + ((gm == gn) ? 2.f : 0.f);
            }
        }
    }
}

// H1[b][h] = relu(sum_i X0[i][b]*W1[i][h] + b1[h]);  X0 [32 x 1024], W1 [32 x 512]
__global__ __launch_bounds__(256)
void mlp1_kernel(const void* __restrict__ X0, const void* __restrict__ W1,
                 const void* __restrict__ b1, float* __restrict__ H1,
                 const int* __restrict__ flag)
{
    const int f32 = flag[0];
    int idx = blockIdx.x * 256 + threadIdx.x;          // 1024*512
    int h = idx & 511, b = idx >> 9;
    float acc = ldf(b1, h, f32);
#pragma unroll
    for (int i = 0; i < 32; i++)
        acc = fmaf(ldf(X0, i * 1024 + b, f32), ldf(W1, i * 512 + h, f32), acc);
    H1[idx] = fmaxf(acc, 0.f);
}

// Bb[b][c] = g[c] + sum_i X0[i][b]*H0[c][i];  H0 [800 x 32]
__global__ __launch_bounds__(256)
void bb_kernel(const void* __restrict__ X0, const void* __restrict__ H0,
               const void* __restrict__ g, float* __restrict__ Bb,
               const int* __restrict__ flag)
{
    const int f32 = flag[0];
    int idx = blockIdx.x * 256 + threadIdx.x;          // 1024*800
    int c = idx % 800, b = idx / 800;
    float acc = ldf(g, c, f32);
#pragma unroll
    for (int i = 0; i < 32; i++)
        acc = fmaf(ldf(X0, i * 1024 + b, f32), ldf(H0, c * 32 + i, f32), acc);
    Bb[(long)b * 800 + c] = acc;
}

__global__ void zero_scal(float* s) { if (threadIdx.x == 0) s[0] = 0.f; }

__global__ __launch_bounds__(256)
void fnorm2_kernel(const float* __restrict__ Km, float* __restrict__ s, int n)
{
    int idx = blockIdx.x * 256 + threadIdx.x;
    float v = (idx < n) ? Km[idx] : 0.f;
    v *= v;
#pragma unroll
    for (int off = 32; off > 0; off >>= 1) v += __shfl_down(v, off, 64);
    __shared__ float ps[4];
    int lane = threadIdx.x & 63, w = threadIdx.x >> 6;
    if (lane == 0) ps[w] = v;
    __syncthreads();
    if (threadIdx.x == 0) atomicAdd(s, ps[0] + ps[1] + ps[2] + ps[3]);
}

// X = t*I with t = 2/(2 + ||K||_F); valid since eig(K) in [2, ||K||_F]
__global__ __launch_bounds__(256)
void xinit_kernel(float* __restrict__ X, const float* __restrict__ s, int n)
{
    int idx = blockIdx.x * 256 + threadIdx.x;
    if (idx >= n) return;
    int i = idx / 400, j = idx % 400;
    float t = 2.f / (2.f + sqrtf(s[0]));
    X[idx] = (i == j) ? t : 0.f;
}

#define GEMM(EPI, TA, TB, AIN, BIN, Ap, Bp, Cp, a1, a2, a3, bia, uba, ob, M_, N_, K_)            \
    gemm_k<EPI, TA, TB, AIN, BIN>                                                                 \
        <<<dim3(((M_) + BM - 1) / BM, ((N_) + BN - 1) / BN), 256, 0, stream>>>(                   \
            Ap, Bp, Cp, a1, a2, a3, bia, uba, ob, flag, M_, N_, K_)

extern "C" void kernel_launch(void* const* d_in, const int* in_sizes, int n_in,
                              void* d_out, int out_size, void* d_ws, size_t ws_size,
                              hipStream_t stream)
{
    const void* X0 = d_in[0];
    const void* W1 = d_in[1];
    const void* b1 = d_in[2];
    const void* W2 = d_in[3];
    const void* b2 = d_in[4];
    const void* W3 = d_in[5];
    const void* b3 = d_in[6];
    const void* ub = d_in[7];
    const void* F  = d_in[8];
    const void* g  = d_in[9];
    const void* H0 = d_in[10];

    float* w = (float*)d_ws;
    size_t off = 0;
    auto alloc = [&](size_t n) { float* p = w + off; off += n; return p; };
    float* H1 = alloc(1024 * 512);
    float* H2 = alloc(1024 * 512);
    float* V  = alloc(1024 * 400);
    float* Bb = alloc(1024 * 800);
    float* Km = alloc(400 * 400);
    float* Xa = alloc(400 * 400);
    float* Xb = alloc(400 * 400);
    float* Yt = alloc(400 * 400);
    float* FK = alloc(800 * 400);
    float* G  = alloc(800 * 800);
    float* C2 = alloc(1024 * 800);
    float* zA = alloc(1024 * 800);
    float* zB = alloc(1024 * 800);
    float* yv = alloc(1024 * 800);
    float* U1 = alloc(1024 * 400);
    float* sc = alloc(16);
    int* flag = (int*)alloc(16);
    (void)ws_size; (void)in_sizes; (void)n_in; (void)out_size;

    const float* NF = nullptr;
    const void*  NV = nullptr;

    // ---- dtype detect (writes flag; every kernel reads it) ----
    detect_kernel<<<1, 256, 0, stream>>>(F, flag);

    // ---- MLP head ----
    mlp1_kernel<<<2048, 256, 0, stream>>>(X0, W1, b1, H1, flag);
    GEMM(EPI_RELU, false, false, false, true, H1, W2, H2, NF, (float*)NF, NF, b2, NV, nullptr, 1024, 512, 512);
    GEMM(EPI_TANH, false, false, false, true, H2, W3, V,  NF, (float*)NF, NF, b3, ub, nullptr, 1024, 400, 512);

    // ---- constraint rhs ----
    bb_kernel<<<3200, 256, 0, stream>>>(X0, H0, g, Bb, flag);

    // ---- K = 2I + F^T F ----
    GEMM(EPI_KMAT, true, false, true, true, F, F, Km, NF, (float*)NF, NF, NV, NV, nullptr, 400, 400, 800);

    // ---- Kinv via Newton-Schulz (quadratic; eig(K) in [2, ||K||_F]) ----
    zero_scal<<<1, 64, 0, stream>>>(sc);
    fnorm2_kernel<<<625, 256, 0, stream>>>(Km, sc, 400 * 400);
    xinit_kernel<<<625, 256, 0, stream>>>(Xa, sc, 400 * 400);
    float* cur = Xa; float* nxt = Xb;
    for (int it = 0; it < 11; it++) {
        GEMM(EPI_PLAIN, false, false, false, false, Km, cur, Yt, NF, (float*)NF, NF, NV, NV, nullptr, 400, 400, 400);
        GEMM(EPI_NS,    false, false, false, false, cur, Yt, nxt, cur, (float*)NF, NF, NV, NV, nullptr, 400, 400, 400);
        float* t = cur; cur = nxt; nxt = t;
    }
    // cur == Kinv

    // ---- precompute FK = F@Kinv, G = FK@F^T, C2 = 2*V@FK^T ----
    GEMM(EPI_PLAIN,  false, false, true,  false, F,  cur, FK, NF, (float*)NF, NF, NV, NV, nullptr, 800, 400, 400);
    GEMM(EPI_SCALE2, false, true,  false, false, V,  FK,  C2, NF, (float*)NF, NF, NV, NV, nullptr, 1024, 800, 400);
    GEMM(EPI_PLAIN,  false, true,  false, true,  FK, F,   G,  NF, (float*)NF, NF, NV, NV, nullptr, 800, 800, 400);

    // ---- zy0 = min(V@F^T, b), y0 = 0 ----
    GEMM(EPI_ZINIT, false, true, false, true, V, F, zA, Bb, yv, NF, NV, NV, nullptr, 1024, 800, 400);

    // ---- ADMM loop: Fu = C2 + zy@G; s = Fu+y; y=max(s-b,0); zy=b-|s-b| ----
    float* zc = zA; float* zn = zB;
    for (int it = 0; it < 40; it++) {
        GEMM(EPI_ADMM, false, false, false, false, zc, G, zn, C2, yv, Bb, NV, NV, nullptr, 1024, 800, 800);
        float* t = zc; zc = zn; zn = t;
    }

    // ---- u = 2*V@Kinv + zy@FK; out = u^T ----
    GEMM(EPI_PLAIN, false, false, false, false, zc, FK, U1, NF, (float*)NF, NF, NV, NV, nullptr, 1024, 400, 800);
    GEMM(EPI_FINAL, false, false, false, false, V, cur, (float*)NF, U1, (float*)NF, NF, NV, NV, d_out, 1024, 400, 400);
}

// Round 3
// 3000.843 us; speedup vs baseline: 2.1386x; 2.1386x over previous
//
#include <hip/hip_runtime.h>
#include <hip/hip_bf16.h>
#include <math.h>

typedef __hip_bfloat16 bf16;
typedef __attribute__((ext_vector_type(8))) short short8;
typedef __attribute__((ext_vector_type(4))) float f32x4;

#define BM 64
#define BN 64
#define BK 16
#define LDP (BM + 4)   // padded LDS leading dim (fp32 vector GEMM)

enum {
    EPI_PLAIN  = 0,
    EPI_RELU   = 1,
    EPI_TANH   = 2,
    EPI_NS     = 3,
    EPI_SCALE2 = 4,
    EPI_ZINIT  = 5,
    EPI_ADMM   = 6,   // (unused now; kept for fallback)
    EPI_FINAL  = 7,
    EPI_KMAT   = 8,
};

// dual-dtype input load: flag==1 -> buffer is float32, else bf16
__device__ __forceinline__ float ldf(const void* p, long i, int f32) {
    return f32 ? ((const float*)p)[i]
               : __bfloat162float(((const bf16*)p)[i]);
}

__device__ __forceinline__ void split_bf16(float z, short& hi, short& lo) {
    bf16 h = __float2bfloat16(z);
    hi = *reinterpret_cast<short*>(&h);
    bf16 l = __float2bfloat16(z - __bfloat162float(h));
    lo = *reinterpret_cast<short*>(&l);
}

// Detect input dtype on-device (bf16 vs fp32-backed): scan F as bf16.
__global__ void detect_kernel(const void* Fp, int* flag) {
    __shared__ int hit;
    if (threadIdx.x == 0) hit = 0;
    __syncthreads();
    const unsigned short* u = (const unsigned short*)Fp;
    int local = 0;
    for (int i = threadIdx.x; i < 16384; i += 256) {
        int e = (u[i] >> 7) & 0xFF;
        if (e >= 0x90) local = 1;
    }
    if (local) atomicOr(&hit, 1);
    __syncthreads();
    if (threadIdx.x == 0) flag[0] = hit;
}

// ---------------- fp32 vector GEMM (small/cold ops) ----------------
template<int EPI, bool TA, bool TB, bool AIN, bool BIN>
__global__ __launch_bounds__(256)
void gemm_k(const void* __restrict__ A, const void* __restrict__ B,
            float* __restrict__ Cout,
            const float* __restrict__ aux1, float* __restrict__ aux2,
            const float* __restrict__ aux3,
            const void* __restrict__ bias, const void* __restrict__ ubar,
            void* __restrict__ outb,
            const int* __restrict__ flag,
            int M, int N, int K)
{
    const int f32 = flag[0];
    __shared__ float As[BK][LDP];
    __shared__ float Bs[BK][LDP];
    const int tid = threadIdx.x;
    const int tx = tid & 15, ty = tid >> 4;
    const int m0 = blockIdx.x * BM, n0 = blockIdx.y * BN;

    float acc[4][4] = {};

    for (int k0 = 0; k0 < K; k0 += BK) {
        if (!TA) {
            int kk = tid & 15, mbase = tid >> 4;
#pragma unroll
            for (int j = 0; j < 4; j++) {
                int m = mbase + j * 16;
                int gm = m0 + m, gk = k0 + kk;
                float v = 0.f;
                if (gm < M && gk < K) {
                    long idx = (long)gm * K + gk;
                    v = AIN ? ldf(A, idx, f32) : ((const float*)A)[idx];
                }
                As[kk][m] = v;
            }
        } else {
            int mm = tid & 63, kbase = tid >> 6;
#pragma unroll
            for (int j = 0; j < 4; j++) {
                int k = kbase + j * 4;
                int gm = m0 + mm, gk = k0 + k;
                float v = 0.f;
                if (gm < M && gk < K) {
                    long idx = (long)gk * M + gm;
                    v = AIN ? ldf(A, idx, f32) : ((const float*)A)[idx];
                }
                As[k][mm] = v;
            }
        }
        if (!TB) {
            int nn = tid & 63, kbase = tid >> 6;
#pragma unroll
            for (int j = 0; j < 4; j++) {
                int k = kbase + j * 4;
                int gn = n0 + nn, gk = k0 + k;
                float v = 0.f;
                if (gn < N && gk < K) {
                    long idx = (long)gk * N + gn;
                    v = BIN ? ldf(B, idx, f32) : ((const float*)B)[idx];
                }
                Bs[k][nn] = v;
            }
        } else {
            int kk = tid & 15, nbase = tid >> 4;
#pragma unroll
            for (int j = 0; j < 4; j++) {
                int n = nbase + j * 16;
                int gn = n0 + n, gk = k0 + kk;
                float v = 0.f;
                if (gn < N && gk < K) {
                    long idx = (long)gn * K + gk;
                    v = BIN ? ldf(B, idx, f32) : ((const float*)B)[idx];
                }
                Bs[kk][n] = v;
            }
        }
        __syncthreads();

#pragma unroll
        for (int kk = 0; kk < BK; kk++) {
            float a[4], b[4];
#pragma unroll
            for (int i = 0; i < 4; i++) a[i] = As[kk][ty * 4 + i];
#pragma unroll
            for (int i = 0; i < 4; i++) b[i] = Bs[kk][tx * 4 + i];
#pragma unroll
            for (int i = 0; i < 4; i++)
#pragma unroll
                for (int j = 0; j < 4; j++)
                    acc[i][j] = fmaf(a[i], b[j], acc[i][j]);
        }
        __syncthreads();
    }

#pragma unroll
    for (int i = 0; i < 4; i++) {
        int gm = m0 + ty * 4 + i;
        if (gm >= M) continue;
#pragma unroll
        for (int j = 0; j < 4; j++) {
            int gn = n0 + tx * 4 + j;
            if (gn >= N) continue;
            long o = (long)gm * N + gn;
            float v = acc[i][j];
            if constexpr (EPI == EPI_PLAIN) {
                Cout[o] = v;
            } else if constexpr (EPI == EPI_RELU) {
                Cout[o] = fmaxf(v + ldf(bias, gn, f32), 0.f);
            } else if constexpr (EPI == EPI_TANH) {
                Cout[o] = tanhf(v + ldf(bias, gn, f32)) * ldf(ubar, gn & 7, f32);
            } else if constexpr (EPI == EPI_NS) {
                Cout[o] = 2.f * aux1[o] - v;
            } else if constexpr (EPI == EPI_SCALE2) {
                Cout[o] = 2.f * v;
            } else if constexpr (EPI == EPI_ZINIT) {
                Cout[o] = fminf(v, aux1[o]);
                aux2[o] = 0.f;
            } else if constexpr (EPI == EPI_ADMM) {
                float s = v + aux1[o] + aux2[o];
                float d = s - aux3[o];
                aux2[o] = fmaxf(d, 0.f);
                Cout[o] = aux3[o] - fabsf(d);
            } else if constexpr (EPI == EPI_FINAL) {
                float val = 2.f * v + aux1[o];
                long oo = (long)gn * M + gm;
                if (f32) ((float*)outb)[oo] = val;
                else     ((bf16*)outb)[oo] = __float2bfloat16(val);
            } else if constexpr (EPI == EPI_KMAT) {
                Cout[o] = v + ((gm == gn) ? 2.f : 0.f);
            }
        }
    }
}

// ---------------- MFMA ADMM iteration ----------------
// Fu = C2 + (zhi+zlo) @ (Ghi+Glo)  [split-3, fp32 acc]
// s = Fu + y; d = s - b; y' = max(d,0); z' = b - |d|; write split(z')
// G padded to 832x832 (zero rim): no bounds checks in K-loop, guard epilogue on gn<800.
// G symmetric => B tile staged from rows of G (coalesced + contiguous ds_read_b128).
template<bool WRITE_F>
__global__ __launch_bounds__(256)
void admm_mfma(const short* __restrict__ zhi, const short* __restrict__ zlo,
               const short* __restrict__ Ghi, const short* __restrict__ Glo,
               const float* __restrict__ C2, float* __restrict__ yv,
               const float* __restrict__ Bb,
               short* __restrict__ zhi_o, short* __restrict__ zlo_o,
               float* __restrict__ zf)
{
    __shared__ __align__(16) short Ah[64][32];
    __shared__ __align__(16) short Al[64][32];
    __shared__ __align__(16) short Bh[64][32];
    __shared__ __align__(16) short Bl[64][32];

    const int tid = threadIdx.x;
    const int m0 = blockIdx.x * 64, n0 = blockIdx.y * 64;
    const int wave = tid >> 6, lane = tid & 63;
    const int wm = (wave & 1) * 32, wn = (wave >> 1) * 32;
    const int q = lane >> 4, r = lane & 15;
    const int sm = tid >> 2, sk = (tid & 3) * 8;    // staging: row sm, 8-elem chunk sk

    f32x4 acc[2][2];
#pragma unroll
    for (int t = 0; t < 2; t++)
#pragma unroll
        for (int u = 0; u < 2; u++)
#pragma unroll
            for (int i = 0; i < 4; i++) acc[t][u][i] = 0.f;

    const long arow = (long)(m0 + sm) * 800 + sk;
    const long brow = (long)(n0 + sm) * 832 + sk;

    for (int k0 = 0; k0 < 800; k0 += 32) {
        *(uint4*)&Ah[sm][sk] = *(const uint4*)&zhi[arow + k0];
        *(uint4*)&Al[sm][sk] = *(const uint4*)&zlo[arow + k0];
        *(uint4*)&Bh[sm][sk] = *(const uint4*)&Ghi[brow + k0];
        *(uint4*)&Bl[sm][sk] = *(const uint4*)&Glo[brow + k0];
        __syncthreads();

        short8 ah[2], al[2], bh[2], bl[2];
#pragma unroll
        for (int t = 0; t < 2; t++) {
            ah[t] = *(const short8*)&Ah[wm + t * 16 + r][q * 8];
            al[t] = *(const short8*)&Al[wm + t * 16 + r][q * 8];
        }
#pragma unroll
        for (int u = 0; u < 2; u++) {
            bh[u] = *(const short8*)&Bh[wn + u * 16 + r][q * 8];
            bl[u] = *(const short8*)&Bl[wn + u * 16 + r][q * 8];
        }
#pragma unroll
        for (int t = 0; t < 2; t++)
#pragma unroll
            for (int u = 0; u < 2; u++) {
                acc[t][u] = __builtin_amdgcn_mfma_f32_16x16x32_bf16(ah[t], bh[u], acc[t][u], 0, 0, 0);
                acc[t][u] = __builtin_amdgcn_mfma_f32_16x16x32_bf16(ah[t], bl[u], acc[t][u], 0, 0, 0);
                acc[t][u] = __builtin_amdgcn_mfma_f32_16x16x32_bf16(al[t], bh[u], acc[t][u], 0, 0, 0);
            }
        __syncthreads();
    }

    // epilogue: C/D layout col=lane&15, row=quad*4+reg (m89-verified)
#pragma unroll
    for (int t = 0; t < 2; t++) {
#pragma unroll
        for (int u = 0; u < 2; u++) {
            int gn = n0 + wn + u * 16 + r;
            if (gn >= 800) continue;
#pragma unroll
            for (int i = 0; i < 4; i++) {
                int gm = m0 + wm + t * 16 + q * 4 + i;
                long o = (long)gm * 800 + gn;
                float s = acc[t][u][i] + C2[o] + yv[o];
                float b = Bb[o];
                float d = s - b;
                yv[o] = fmaxf(d, 0.f);
                float z = b - fabsf(d);
                short h, l;
                split_bf16(z, h, l);
                zhi_o[o] = h;
                zlo_o[o] = l;
                if constexpr (WRITE_F) zf[o] = z;
            }
        }
    }
}

// split G (800x800 fp32) -> padded 832x832 bf16 hi/lo
__global__ __launch_bounds__(256)
void gsplit_kernel(const float* __restrict__ G, short* __restrict__ Ghi, short* __restrict__ Glo)
{
    int idx = blockIdx.x * 256 + threadIdx.x;
    if (idx >= 832 * 832) return;
    int i = idx / 832, j = idx % 832;
    float v = (i < 800 && j < 800) ? G[i * 800 + j] : 0.f;
    short h, l;
    split_bf16(v, h, l);
    Ghi[idx] = h;
    Glo[idx] = l;
}

// split z0 (1024x800 fp32) -> bf16 hi/lo
__global__ __launch_bounds__(256)
void zsplit_kernel(const float* __restrict__ z, short* __restrict__ zh, short* __restrict__ zl)
{
    int idx = blockIdx.x * 256 + threadIdx.x;
    if (idx >= 1024 * 800) return;
    short h, l;
    split_bf16(z[idx], h, l);
    zh[idx] = h;
    zl[idx] = l;
}

// ---------------- misc small kernels ----------------
__global__ __launch_bounds__(256)
void mlp1_kernel(const void* __restrict__ X0, const void* __restrict__ W1,
                 const void* __restrict__ b1, float* __restrict__ H1,
                 const int* __restrict__ flag)
{
    const int f32 = flag[0];
    int idx = blockIdx.x * 256 + threadIdx.x;
    int h = idx & 511, b = idx >> 9;
    float acc = ldf(b1, h, f32);
#pragma unroll
    for (int i = 0; i < 32; i++)
        acc = fmaf(ldf(X0, i * 1024 + b, f32), ldf(W1, i * 512 + h, f32), acc);
    H1[idx] = fmaxf(acc, 0.f);
}

__global__ __launch_bounds__(256)
void bb_kernel(const void* __restrict__ X0, const void* __restrict__ H0,
               const void* __restrict__ g, float* __restrict__ Bb,
               const int* __restrict__ flag)
{
    const int f32 = flag[0];
    int idx = blockIdx.x * 256 + threadIdx.x;
    int c = idx % 800, b = idx / 800;
    float acc = ldf(g, c, f32);
#pragma unroll
    for (int i = 0; i < 32; i++)
        acc = fmaf(ldf(X0, i * 1024 + b, f32), ldf(H0, c * 32 + i, f32), acc);
    Bb[(long)b * 800 + c] = acc;
}

__global__ void zero_scal(float* s) { if (threadIdx.x == 0) s[0] = 0.f; }

__global__ __launch_bounds__(256)
void fnorm2_kernel(const float* __restrict__ Km, float* __restrict__ s, int n)
{
    int idx = blockIdx.x * 256 + threadIdx.x;
    float v = (idx < n) ? Km[idx] : 0.f;
    v *= v;
#pragma unroll
    for (int off = 32; off > 0; off >>= 1) v += __shfl_down(v, off, 64);
    __shared__ float ps[4];
    int lane = threadIdx.x & 63, w = threadIdx.x >> 6;
    if (lane == 0) ps[w] = v;
    __syncthreads();
    if (threadIdx.x == 0) atomicAdd(s, ps[0] + ps[1] + ps[2] + ps[3]);
}

__global__ __launch_bounds__(256)
void xinit_kernel(float* __restrict__ X, const float* __restrict__ s, int n)
{
    int idx = blockIdx.x * 256 + threadIdx.x;
    if (idx >= n) return;
    int i = idx / 400, j = idx % 400;
    float t = 2.f / (2.f + sqrtf(s[0]));
    X[idx] = (i == j) ? t : 0.f;
}

#define GEMM(EPI, TA, TB, AIN, BIN, Ap, Bp, Cp, a1, a2, a3, bia, uba, ob, M_, N_, K_)            \
    gemm_k<EPI, TA, TB, AIN, BIN>                                                                 \
        <<<dim3(((M_) + BM - 1) / BM, ((N_) + BN - 1) / BN), 256, 0, stream>>>(                   \
            Ap, Bp, Cp, a1, a2, a3, bia, uba, ob, flag, M_, N_, K_)

extern "C" void kernel_launch(void* const* d_in, const int* in_sizes, int n_in,
                              void* d_out, int out_size, void* d_ws, size_t ws_size,
                              hipStream_t stream)
{
    const void* X0 = d_in[0];
    const void* W1 = d_in[1];
    const void* b1 = d_in[2];
    const void* W2 = d_in[3];
    const void* b2 = d_in[4];
    const void* W3 = d_in[5];
    const void* b3 = d_in[6];
    const void* ub = d_in[7];
    const void* F  = d_in[8];
    const void* g  = d_in[9];
    const void* H0 = d_in[10];

    float* w = (float*)d_ws;
    size_t off = 0;
    auto alloc = [&](size_t n) { float* p = w + off; off += n; return p; };
    float* H1 = alloc(1024 * 512);
    float* H2 = alloc(1024 * 512);
    float* V  = alloc(1024 * 400);
    float* Bb = alloc(1024 * 800);
    float* Km = alloc(400 * 400);
    float* Xa = alloc(400 * 400);
    float* Xb = alloc(400 * 400);
    float* Yt = alloc(400 * 400);
    float* FK = alloc(800 * 400);
    float* G  = alloc(800 * 800);
    float* C2 = alloc(1024 * 800);
    float* zA = alloc(1024 * 800);
    float* yv = alloc(1024 * 800);
    float* U1 = alloc(1024 * 400);
    short* GhiS = (short*)alloc(832 * 832 / 2);
    short* GloS = (short*)alloc(832 * 832 / 2);
    short* zhiA = (short*)alloc(1024 * 800 / 2);
    short* zloA = (short*)alloc(1024 * 800 / 2);
    short* zhiB = (short*)alloc(1024 * 800 / 2);
    short* zloB = (short*)alloc(1024 * 800 / 2);
    float* sc = alloc(16);
    int* flag = (int*)alloc(16);
    (void)ws_size; (void)in_sizes; (void)n_in; (void)out_size;

    const float* NF = nullptr;
    const void*  NV = nullptr;

    // ---- dtype detect ----
    detect_kernel<<<1, 256, 0, stream>>>(F, flag);

    // ---- MLP head ----
    mlp1_kernel<<<2048, 256, 0, stream>>>(X0, W1, b1, H1, flag);
    GEMM(EPI_RELU, false, false, false, true, H1, W2, H2, NF, (float*)NF, NF, b2, NV, nullptr, 1024, 512, 512);
    GEMM(EPI_TANH, false, false, false, true, H2, W3, V,  NF, (float*)NF, NF, b3, ub, nullptr, 1024, 400, 512);

    // ---- constraint rhs ----
    bb_kernel<<<3200, 256, 0, stream>>>(X0, H0, g, Bb, flag);

    // ---- K = 2I + F^T F ----
    GEMM(EPI_KMAT, true, false, true, true, F, F, Km, NF, (float*)NF, NF, NV, NV, nullptr, 400, 400, 800);

    // ---- Kinv via Newton-Schulz ----
    zero_scal<<<1, 64, 0, stream>>>(sc);
    fnorm2_kernel<<<625, 256, 0, stream>>>(Km, sc, 400 * 400);
    xinit_kernel<<<625, 256, 0, stream>>>(Xa, sc, 400 * 400);
    float* cur = Xa; float* nxt = Xb;
    for (int it = 0; it < 11; it++) {
        GEMM(EPI_PLAIN, false, false, false, false, Km, cur, Yt, NF, (float*)NF, NF, NV, NV, nullptr, 400, 400, 400);
        GEMM(EPI_NS,    false, false, false, false, cur, Yt, nxt, cur, (float*)NF, NF, NV, NV, nullptr, 400, 400, 400);
        float* t = cur; cur = nxt; nxt = t;
    }

    // ---- FK = F@Kinv, C2 = 2*V@FK^T, G = FK@F^T ----
    GEMM(EPI_PLAIN,  false, false, true,  false, F,  cur, FK, NF, (float*)NF, NF, NV, NV, nullptr, 800, 400, 400);
    GEMM(EPI_SCALE2, false, true,  false, false, V,  FK,  C2, NF, (float*)NF, NF, NV, NV, nullptr, 1024, 800, 400);
    GEMM(EPI_PLAIN,  false, true,  false, true,  FK, F,   G,  NF, (float*)NF, NF, NV, NV, nullptr, 800, 800, 400);

    // ---- zy0 = min(V@F^T, b), y0 = 0; split for MFMA ----
    GEMM(EPI_ZINIT, false, true, false, true, V, F, zA, Bb, yv, NF, NV, NV, nullptr, 1024, 800, 400);
    gsplit_kernel<<<(832 * 832 + 255) / 256, 256, 0, stream>>>(G, GhiS, GloS);
    zsplit_kernel<<<(1024 * 800 + 255) / 256, 256, 0, stream>>>(zA, zhiA, zloA);

    // ---- ADMM loop (MFMA, split-3) ----
    short* zh_c = zhiA; short* zl_c = zloA;
    short* zh_n = zhiB; short* zl_n = zloB;
    for (int it = 0; it < 40; it++) {
        if (it == 39)
            admm_mfma<true><<<dim3(16, 13), 256, 0, stream>>>(zh_c, zl_c, GhiS, GloS, C2, yv, Bb, zh_n, zl_n, zA);
        else
            admm_mfma<false><<<dim3(16, 13), 256, 0, stream>>>(zh_c, zl_c, GhiS, GloS, C2, yv, Bb, zh_n, zl_n, zA);
        short* t;
        t = zh_c; zh_c = zh_n; zh_n = t;
        t = zl_c; zl_c = zl_n; zl_n = t;
    }
    // zA holds final zy (fp32)

    // ---- u = 2*V@Kinv + zy@FK; out = u^T ----
    GEMM(EPI_PLAIN, false, false, false, false, zA, FK, U1, NF, (float*)NF, NF, NV, NV, nullptr, 1024, 400, 800);
    GEMM(EPI_FINAL, false, false, false, false, V, cur, (float*)NF, U1, (float*)NF, NF, NV, NV, d_out, 1024, 400, 400);
}

// Round 4
// 1491.971 us; speedup vs baseline: 4.3015x; 2.0113x over previous
//
#include <hip/hip_runtime.h>
#include <hip/hip_bf16.h>
#include <math.h>

typedef __hip_bfloat16 bf16;
typedef __attribute__((ext_vector_type(8))) short short8;
typedef __attribute__((ext_vector_type(4))) float f32x4;

// ---------- epilogue ids ----------
enum {
    M_H2 = 0,   // relu(acc + bias[gn]) -> split
    M_V,        // tanh(acc + bias[gn]) * ub[gn&7] -> split (Nreal 400, pad 416)
    M_KM,       // acc + 2*(m==n) -> split Kms + fp32 Km[400x400]
    M_W,        // acc -> split (Ws)
    M_NS,       // 2*Xf - acc -> split + fp32 Xf'
    M_FK,       // acc -> split FKs + transposed split FKts
    M_G,        // acc -> split Gs (832 exact)
    M_C2,       // 2*acc -> fp32 C2 (gn<800)
    M_ZI,       // z=min(acc,Bb); yv=0 -> split z (gn<800)
    M_U1,       // acc -> fp32 U1 (gn<400)
    M_FIN,      // 2*acc + U1 -> out[gn*1024+gm] (gn<400), dtype per flag
};

// dual-dtype input load: flag==1 -> fp32, else bf16
__device__ __forceinline__ float ldf(const void* p, long i, int f32) {
    return f32 ? ((const float*)p)[i]
               : __bfloat162float(((const bf16*)p)[i]);
}

__device__ __forceinline__ void split_bf16(float z, short& hi, short& lo) {
    bf16 h = __float2bfloat16(z);
    hi = *reinterpret_cast<short*>(&h);
    bf16 l = __float2bfloat16(z - __bfloat162float(h));
    lo = *reinterpret_cast<short*>(&l);
}
__device__ __forceinline__ void sstore(short* H, short* L, long o, float v) {
    short h, l; split_bf16(v, h, l); H[o] = h; L[o] = l;
}

// ---------- dtype detect ----------
__global__ void detect_kernel(const void* Fp, int* flag) {
    __shared__ int hit;
    if (threadIdx.x == 0) hit = 0;
    __syncthreads();
    const unsigned short* u = (const unsigned short*)Fp;
    int local = 0;
    for (int i = threadIdx.x; i < 16384; i += 256) {
        int e = (u[i] >> 7) & 0xFF;
        if (e >= 0x90) local = 1;
    }
    if (local) atomicOr(&hit, 1);
    __syncthreads();
    if (threadIdx.x == 0) flag[0] = hit;
}

// ---------- generic split-3 MFMA GEMM, 64x64 tile ----------
// C[m][n] = sum_k A[m][k] * Bt[n][k]   (Bt rows are B^T rows)
template<int EPI>
__global__ __launch_bounds__(256)
void mgemm(const short* __restrict__ Ah, const short* __restrict__ Al, int sA,
           const short* __restrict__ Bth, const short* __restrict__ Btl, int sB,
           int KC,
           short* __restrict__ Oh, short* __restrict__ Ol, int sO,
           short* __restrict__ Oth, short* __restrict__ Otl,
           float* __restrict__ fout, const float* __restrict__ faux,
           const void* __restrict__ bias, const void* __restrict__ ubp,
           void* __restrict__ rawout, const int* __restrict__ flag)
{
    __shared__ __align__(16) short Ahs[64][32];
    __shared__ __align__(16) short Als[64][32];
    __shared__ __align__(16) short Bhs[64][32];
    __shared__ __align__(16) short Bls[64][32];

    const int tid = threadIdx.x;
    const int m0 = blockIdx.x * 64, n0 = blockIdx.y * 64;
    const int wave = tid >> 6, lane = tid & 63;
    const int wm = (wave & 1) * 32, wn = (wave >> 1) * 32;
    const int q = lane >> 4, r = lane & 15;
    const int sm = tid >> 2, sk = (tid & 3) * 8;

    f32x4 acc[2][2];
#pragma unroll
    for (int t = 0; t < 2; t++)
#pragma unroll
        for (int u = 0; u < 2; u++)
#pragma unroll
            for (int i = 0; i < 4; i++) acc[t][u][i] = 0.f;

    const long arow = (long)(m0 + sm) * sA + sk;
    const long brow = (long)(n0 + sm) * sB + sk;

    for (int c = 0; c < KC; c++) {
        const int k0 = c * 32;
        *(uint4*)&Ahs[sm][sk] = *(const uint4*)&Ah[arow + k0];
        *(uint4*)&Als[sm][sk] = *(const uint4*)&Al[arow + k0];
        *(uint4*)&Bhs[sm][sk] = *(const uint4*)&Bth[brow + k0];
        *(uint4*)&Bls[sm][sk] = *(const uint4*)&Btl[brow + k0];
        __syncthreads();

        short8 a_h[2], a_l[2], b_h[2], b_l[2];
#pragma unroll
        for (int t = 0; t < 2; t++) {
            a_h[t] = *(const short8*)&Ahs[wm + t * 16 + r][q * 8];
            a_l[t] = *(const short8*)&Als[wm + t * 16 + r][q * 8];
        }
#pragma unroll
        for (int u = 0; u < 2; u++) {
            b_h[u] = *(const short8*)&Bhs[wn + u * 16 + r][q * 8];
            b_l[u] = *(const short8*)&Bls[wn + u * 16 + r][q * 8];
        }
#pragma unroll
        for (int t = 0; t < 2; t++)
#pragma unroll
            for (int u = 0; u < 2; u++) {
                acc[t][u] = __builtin_amdgcn_mfma_f32_16x16x32_bf16(a_h[t], b_h[u], acc[t][u], 0, 0, 0);
                acc[t][u] = __builtin_amdgcn_mfma_f32_16x16x32_bf16(a_h[t], b_l[u], acc[t][u], 0, 0, 0);
                acc[t][u] = __builtin_amdgcn_mfma_f32_16x16x32_bf16(a_l[t], b_h[u], acc[t][u], 0, 0, 0);
            }
        __syncthreads();
    }

    const int f32 = flag[0];
    // C/D layout: col = lane&15 (gn), row = quad*4 + reg (gm)  [m89-verified]
#pragma unroll
    for (int t = 0; t < 2; t++) {
#pragma unroll
        for (int u = 0; u < 2; u++) {
            int gn = n0 + wn + u * 16 + r;
#pragma unroll
            for (int i = 0; i < 4; i++) {
                int gm = m0 + wm + t * 16 + q * 4 + i;
                float v = acc[t][u][i];
                if constexpr (EPI == M_H2) {
                    float val = fmaxf(v + ldf(bias, gn, f32), 0.f);
                    sstore(Oh, Ol, (long)gm * sO + gn, val);
                } else if constexpr (EPI == M_V) {
                    if (gn < 416) {
                        float val = 0.f;
                        if (gn < 400)
                            val = tanhf(v + ldf(bias, gn, f32)) * ldf(ubp, gn & 7, f32);
                        sstore(Oh, Ol, (long)gm * sO + gn, val);
                    }
                } else if constexpr (EPI == M_KM) {
                    if (gn < 416) {
                        float val = 0.f;
                        if (gm < 400 && gn < 400) {
                            val = v + ((gm == gn) ? 2.f : 0.f);
                            fout[gm * 400 + gn] = val;
                        }
                        sstore(Oh, Ol, (long)gm * sO + gn, val);
                    }
                } else if constexpr (EPI == M_W) {
                    if (gn < 416) sstore(Oh, Ol, (long)gm * sO + gn, v);
                } else if constexpr (EPI == M_NS) {
                    if (gn < 416) {
                        float val = 0.f;
                        if (gm < 400 && gn < 400) {
                            val = 2.f * faux[gm * 400 + gn] - v;
                            fout[gm * 400 + gn] = val;
                        }
                        sstore(Oh, Ol, (long)gm * sO + gn, val);
                    }
                } else if constexpr (EPI == M_FK) {
                    if (gn < 416) sstore(Oh, Ol, (long)gm * sO + gn, v);
                    if (gm < 800) sstore(Oth, Otl, (long)gn * 800 + gm, v);
                } else if constexpr (EPI == M_G) {
                    sstore(Oh, Ol, (long)gm * sO + gn, v);
                } else if constexpr (EPI == M_C2) {
                    if (gn < 800) fout[(long)gm * 800 + gn] = 2.f * v;
                } else if constexpr (EPI == M_ZI) {
                    if (gn < 800) {
                        long o = (long)gm * 800 + gn;
                        float z = fminf(v, faux[o]);
                        fout[o] = 0.f;   // yv = 0
                        sstore(Oh, Ol, o, z);
                    }
                } else if constexpr (EPI == M_U1) {
                    if (gn < 400) fout[(long)gm * 400 + gn] = v;
                } else if constexpr (EPI == M_FIN) {
                    if (gn < 400) {
                        float val = 2.f * v + faux[(long)gm * 400 + gn];
                        long oo = (long)gn * 1024 + gm;
                        if (f32) ((float*)rawout)[oo] = val;
                        else     ((bf16*)rawout)[oo] = __float2bfloat16(val);
                    }
                }
            }
        }
    }
}

// ---------- ADMM iteration (unchanged structure from round 3) ----------
__global__ __launch_bounds__(256)
void admm_mfma(const short* __restrict__ zhi, const short* __restrict__ zlo,
               const short* __restrict__ Ghi, const short* __restrict__ Glo,
               const float* __restrict__ C2, float* __restrict__ yv,
               const float* __restrict__ Bb,
               short* __restrict__ zhi_o, short* __restrict__ zlo_o)
{
    __shared__ __align__(16) short Ahs[64][32];
    __shared__ __align__(16) short Als[64][32];
    __shared__ __align__(16) short Bhs[64][32];
    __shared__ __align__(16) short Bls[64][32];

    const int tid = threadIdx.x;
    const int m0 = blockIdx.x * 64, n0 = blockIdx.y * 64;
    const int wave = tid >> 6, lane = tid & 63;
    const int wm = (wave & 1) * 32, wn = (wave >> 1) * 32;
    const int q = lane >> 4, r = lane & 15;
    const int sm = tid >> 2, sk = (tid & 3) * 8;

    f32x4 acc[2][2];
#pragma unroll
    for (int t = 0; t < 2; t++)
#pragma unroll
        for (int u = 0; u < 2; u++)
#pragma unroll
            for (int i = 0; i < 4; i++) acc[t][u][i] = 0.f;

    const long arow = (long)(m0 + sm) * 800 + sk;
    const long brow = (long)(n0 + sm) * 832 + sk;

    for (int k0 = 0; k0 < 800; k0 += 32) {
        *(uint4*)&Ahs[sm][sk] = *(const uint4*)&zhi[arow + k0];
        *(uint4*)&Als[sm][sk] = *(const uint4*)&zlo[arow + k0];
        *(uint4*)&Bhs[sm][sk] = *(const uint4*)&Ghi[brow + k0];
        *(uint4*)&Bls[sm][sk] = *(const uint4*)&Glo[brow + k0];
        __syncthreads();

        short8 a_h[2], a_l[2], b_h[2], b_l[2];
#pragma unroll
        for (int t = 0; t < 2; t++) {
            a_h[t] = *(const short8*)&Ahs[wm + t * 16 + r][q * 8];
            a_l[t] = *(const short8*)&Als[wm + t * 16 + r][q * 8];
        }
#pragma unroll
        for (int u = 0; u < 2; u++) {
            b_h[u] = *(const short8*)&Bhs[wn + u * 16 + r][q * 8];
            b_l[u] = *(const short8*)&Bls[wn + u * 16 + r][q * 8];
        }
#pragma unroll
        for (int t = 0; t < 2; t++)
#pragma unroll
            for (int u = 0; u < 2; u++) {
                acc[t][u] = __builtin_amdgcn_mfma_f32_16x16x32_bf16(a_h[t], b_h[u], acc[t][u], 0, 0, 0);
                acc[t][u] = __builtin_amdgcn_mfma_f32_16x16x32_bf16(a_h[t], b_l[u], acc[t][u], 0, 0, 0);
                acc[t][u] = __builtin_amdgcn_mfma_f32_16x16x32_bf16(a_l[t], b_h[u], acc[t][u], 0, 0, 0);
            }
        __syncthreads();
    }

#pragma unroll
    for (int t = 0; t < 2; t++) {
#pragma unroll
        for (int u = 0; u < 2; u++) {
            int gn = n0 + wn + u * 16 + r;
            if (gn >= 800) continue;
#pragma unroll
            for (int i = 0; i < 4; i++) {
                int gm = m0 + wm + t * 16 + q * 4 + i;
                long o = (long)gm * 800 + gn;
                float s = acc[t][u][i] + C2[o] + yv[o];
                float b = Bb[o];
                float d = s - b;
                yv[o] = fmaxf(d, 0.f);
                sstore(zhi_o, zlo_o, o, b - fabsf(d));
            }
        }
    }
}

// ---------- prep kernels ----------
// pad+split (no transpose): dst[m][k] = src[m*K_+k]
__global__ __launch_bounds__(256)
void padsplit_kernel(const void* __restrict__ src, short* __restrict__ dh, short* __restrict__ dl,
                     int M_, int K_, int dstride, const int* __restrict__ flag)
{
    const int f32 = flag[0];
    int idx = blockIdx.x * 256 + threadIdx.x;
    if (idx >= M_ * K_) return;
    int m = idx / K_, k = idx % K_;
    sstore(dh, dl, (long)m * dstride + k, ldf(src, idx, f32));
}
// transpose+split: dst[n][k] = src[k*N_+n]
__global__ __launch_bounds__(256)
void transsplit_kernel(const void* __restrict__ src, short* __restrict__ dh, short* __restrict__ dl,
                       int N_, int K_, int dstride, const int* __restrict__ flag)
{
    const int f32 = flag[0];
    int idx = blockIdx.x * 256 + threadIdx.x;
    if (idx >= N_ * K_) return;
    int n = idx / K_, k = idx % K_;
    sstore(dh, dl, (long)n * dstride + k, ldf(src, (long)k * N_ + n, f32));
}

// H1 = relu(X0^T@W1 + b1) -> split
__global__ __launch_bounds__(256)
void mlp1_kernel(const void* __restrict__ X0, const void* __restrict__ W1,
                 const void* __restrict__ b1, short* __restrict__ Hh, short* __restrict__ Hl,
                 const int* __restrict__ flag)
{
    const int f32 = flag[0];
    int idx = blockIdx.x * 256 + threadIdx.x;
    int h = idx & 511, b = idx >> 9;
    float acc = ldf(b1, h, f32);
#pragma unroll
    for (int i = 0; i < 32; i++)
        acc = fmaf(ldf(X0, i * 1024 + b, f32), ldf(W1, i * 512 + h, f32), acc);
    sstore(Hh, Hl, idx, fmaxf(acc, 0.f));
}

__global__ __launch_bounds__(256)
void bb_kernel(const void* __restrict__ X0, const void* __restrict__ H0,
               const void* __restrict__ g, float* __restrict__ Bb,
               const int* __restrict__ flag)
{
    const int f32 = flag[0];
    int idx = blockIdx.x * 256 + threadIdx.x;
    int c = idx % 800, b = idx / 800;
    float acc = ldf(g, c, f32);
#pragma unroll
    for (int i = 0; i < 32; i++)
        acc = fmaf(ldf(X0, i * 1024 + b, f32), ldf(H0, c * 32 + i, f32), acc);
    Bb[(long)b * 800 + c] = acc;
}

__global__ void zero_scal(float* s) { if (threadIdx.x == 0) s[0] = 0.f; }

__global__ __launch_bounds__(256)
void fnorm2_kernel(const float* __restrict__ Km, float* __restrict__ s, int n)
{
    int idx = blockIdx.x * 256 + threadIdx.x;
    float v = (idx < n) ? Km[idx] : 0.f;
    v *= v;
#pragma unroll
    for (int off = 32; off > 0; off >>= 1) v += __shfl_down(v, off, 64);
    __shared__ float ps[4];
    int lane = threadIdx.x & 63, w = threadIdx.x >> 6;
    if (lane == 0) ps[w] = v;
    __syncthreads();
    if (threadIdx.x == 0) atomicAdd(s, ps[0] + ps[1] + ps[2] + ps[3]);
}

// X0 = t*I (fp32 + split), t = 2/(2 + ||K||_F)
__global__ __launch_bounds__(256)
void xinit_kernel(float* __restrict__ Xf, short* __restrict__ Xh, short* __restrict__ Xl,
                  const float* __restrict__ s)
{
    int idx = blockIdx.x * 256 + threadIdx.x;
    if (idx >= 400 * 400) return;
    int i = idx / 400, j = idx % 400;
    float t = 2.f / (2.f + sqrtf(s[0]));
    float v = (i == j) ? t : 0.f;
    Xf[idx] = v;
    sstore(Xh, Xl, (long)i * 416 + j, v);
}

extern "C" void kernel_launch(void* const* d_in, const int* in_sizes, int n_in,
                              void* d_out, int out_size, void* d_ws, size_t ws_size,
                              hipStream_t stream)
{
    const void* X0 = d_in[0];
    const void* W1 = d_in[1];
    const void* b1 = d_in[2];
    const void* W2 = d_in[3];
    const void* b2 = d_in[4];
    const void* W3 = d_in[5];
    const void* b3 = d_in[6];
    const void* ub = d_in[7];
    const void* F  = d_in[8];
    const void* g  = d_in[9];
    const void* H0 = d_in[10];
    (void)in_sizes; (void)n_in; (void)out_size; (void)ws_size;

    char* w = (char*)d_ws;
    size_t off = 0;
    auto allocb = [&](size_t bytes) { char* p = w + off; off += (bytes + 15) & ~size_t(15); return p; };

    // fp32 region
    float* Km  = (float*)allocb(400 * 400 * 4);
    float* XfA = (float*)allocb(400 * 400 * 4);
    float* XfB = (float*)allocb(400 * 400 * 4);
    float* Bb  = (float*)allocb(1024 * 800 * 4);
    float* C2  = (float*)allocb(1024 * 800 * 4);
    float* yv  = (float*)allocb(1024 * 800 * 4);
    float* U1  = (float*)allocb(1024 * 400 * 4);
    float* sc  = (float*)allocb(64);
    int*  flag = (int*)allocb(64);

    // split region (contiguous; memset once per call)
    char* split_base = w + off;
    auto allocs = [&](size_t n) { return (short*)allocb(n * 2); };
    short *W2h = allocs(512*512), *W2l = allocs(512*512);
    short *W3h = allocs(448*512), *W3l = allocs(448*512);
    short *H1h = allocs(1024*512), *H1l = allocs(1024*512);
    short *H2h = allocs(1024*512), *H2l = allocs(1024*512);
    short *Vh  = allocs(1024*416), *Vl  = allocs(1024*416);
    short *Fsh = allocs(832*416),  *Fsl = allocs(832*416);
    short *Fth = allocs(448*800),  *Ftl = allocs(448*800);
    short *Kmh = allocs(448*416),  *Kml = allocs(448*416);
    short *XAh = allocs(448*416),  *XAl = allocs(448*416);
    short *XBh = allocs(448*416),  *XBl = allocs(448*416);
    short *Wsh = allocs(448*416),  *Wsl = allocs(448*416);
    short *FKh = allocs(832*416),  *FKl = allocs(832*416);
    short *FTh = allocs(448*800),  *FTl = allocs(448*800);
    short *Gh  = allocs(832*832),  *Gl  = allocs(832*832);
    short *zAh = allocs(1024*800), *zAl = allocs(1024*800);
    short *zBh = allocs(1024*800), *zBl = allocs(1024*800);
    size_t split_bytes = (size_t)((w + off) - split_base);

    const short* NS_ = nullptr; short* NSo = nullptr;
    const float* NF = nullptr; float* NFo = nullptr;
    const void* NV = nullptr;

    // ---- dtype detect + rim zeroing ----
    detect_kernel<<<1, 256, 0, stream>>>(F, flag);
    hipMemsetAsync(split_base, 0, split_bytes, stream);

    // ---- input prep (pad/transpose + split) ----
    padsplit_kernel<<<(800*400+255)/256, 256, 0, stream>>>(F, Fsh, Fsl, 800, 400, 416, flag);
    transsplit_kernel<<<(400*800+255)/256, 256, 0, stream>>>(F, Fth, Ftl, 400, 800, 800, flag);
    transsplit_kernel<<<(512*512+255)/256, 256, 0, stream>>>(W2, W2h, W2l, 512, 512, 512, flag);
    transsplit_kernel<<<(400*512+255)/256, 256, 0, stream>>>(W3, W3h, W3l, 400, 512, 512, flag);

    // ---- MLP head ----
    mlp1_kernel<<<2048, 256, 0, stream>>>(X0, W1, b1, H1h, H1l, flag);
    mgemm<M_H2><<<dim3(16, 8), 256, 0, stream>>>(H1h, H1l, 512, W2h, W2l, 512, 16,
        H2h, H2l, 512, NSo, NSo, NFo, NF, b2, NV, nullptr, flag);
    mgemm<M_V><<<dim3(16, 7), 256, 0, stream>>>(H2h, H2l, 512, W3h, W3l, 512, 16,
        Vh, Vl, 416, NSo, NSo, NFo, NF, b3, ub, nullptr, flag);

    // ---- constraint rhs ----
    bb_kernel<<<3200, 256, 0, stream>>>(X0, H0, g, Bb, flag);

    // ---- Km = 2I + F^T F ----
    mgemm<M_KM><<<dim3(7, 7), 256, 0, stream>>>(Fth, Ftl, 800, Fth, Ftl, 800, 25,
        Kmh, Kml, 416, NSo, NSo, Km, NF, NV, NV, nullptr, flag);

    // ---- Kinv via Newton-Schulz: W = X@Km; X' = 2X - W@X ----
    zero_scal<<<1, 64, 0, stream>>>(sc);
    fnorm2_kernel<<<625, 256, 0, stream>>>(Km, sc, 400 * 400);
    xinit_kernel<<<625, 256, 0, stream>>>(XfA, XAh, XAl, sc);
    short *Xch = XAh, *Xcl = XAl, *Xnh = XBh, *Xnl = XBl;
    float *Xfc = XfA, *Xfn = XfB;
    for (int it = 0; it < 11; it++) {
        mgemm<M_W><<<dim3(7, 7), 256, 0, stream>>>(Xch, Xcl, 416, Kmh, Kml, 416, 13,
            Wsh, Wsl, 416, NSo, NSo, NFo, NF, NV, NV, nullptr, flag);
        mgemm<M_NS><<<dim3(7, 7), 256, 0, stream>>>(Wsh, Wsl, 416, Xch, Xcl, 416, 13,
            Xnh, Xnl, 416, NSo, NSo, Xfn, Xfc, NV, NV, nullptr, flag);
        short* t;
        t = Xch; Xch = Xnh; Xnh = t;
        t = Xcl; Xcl = Xnl; Xnl = t;
        float* tf = Xfc; Xfc = Xfn; Xfn = tf;
    }
    // (Xch,Xcl) == Kinv split (symmetric)

    // ---- FK = F@Kinv (+FK^T), C2 = 2V@FK^T, G = FK@F^T ----
    mgemm<M_FK><<<dim3(13, 7), 256, 0, stream>>>(Fsh, Fsl, 416, Xch, Xcl, 416, 13,
        FKh, FKl, 416, FTh, FTl, NFo, NF, NV, NV, nullptr, flag);
    mgemm<M_C2><<<dim3(16, 13), 256, 0, stream>>>(Vh, Vl, 416, FKh, FKl, 416, 13,
        NSo, NSo, 0, NSo, NSo, C2, NF, NV, NV, nullptr, flag);
    mgemm<M_G><<<dim3(13, 13), 256, 0, stream>>>(FKh, FKl, 416, Fsh, Fsl, 416, 13,
        Gh, Gl, 832, NSo, NSo, NFo, NF, NV, NV, nullptr, flag);

    // ---- z0 = min(V@F^T, Bb), y0 = 0 ----
    mgemm<M_ZI><<<dim3(16, 13), 256, 0, stream>>>(Vh, Vl, 416, Fsh, Fsl, 416, 13,
        zAh, zAl, 800, NSo, NSo, yv, Bb, NV, NV, nullptr, flag);

    // ---- ADMM loop ----
    short *zch = zAh, *zcl = zAl, *znh = zBh, *znl = zBl;
    for (int it = 0; it < 40; it++) {
        admm_mfma<<<dim3(16, 13), 256, 0, stream>>>(zch, zcl, Gh, Gl, C2, yv, Bb, znh, znl);
        short* t;
        t = zch; zch = znh; znh = t;
        t = zcl; zcl = znl; znl = t;
    }

    // ---- U1 = zy@FK; out = (2V@Kinv + U1)^T ----
    mgemm<M_U1><<<dim3(16, 7), 256, 0, stream>>>(zch, zcl, 800, FTh, FTl, 800, 25,
        NSo, NSo, 0, NSo, NSo, U1, NF, NV, NV, nullptr, flag);
    mgemm<M_FIN><<<dim3(16, 7), 256, 0, stream>>>(Vh, Vl, 416, Xch, Xcl, 416, 13,
        NSo, NSo, 0, NSo, NSo, NFo, U1, NV, NV, d_out, flag);
}